// Round 1
// baseline (46.294 us; speedup 1.0000x reference)
//
#include <hip/hip_runtime.h>
#include <math.h>

// Spline geometry (uniform knots): lo = -18, dist = 36/29
#define SP_LO       (-18.0f)
#define SP_INV_DIST (29.0f / 36.0f)
#define NEG_HALF_LOG_2PI (-0.91893853320467274f)

// ---------------------------------------------------------------------------
// Kernel 1: tiny, single-thread — monotonic coef transform + derivative coefs
//   ws[0..31]  = coefs (c0 = p0, ck = c0 + cumsum(softplus(p1..pk)))
//   ws[32..62] = dcoefs[i] = (c[i+1]-c[i]) / dist
// ---------------------------------------------------------------------------
__global__ void TM_precompute(const float* __restrict__ params,
                              float* __restrict__ ws) {
    if (threadIdx.x == 0 && blockIdx.x == 0) {
        float acc = params[0];
        ws[0] = acc;
        for (int k = 1; k < 32; ++k) {
            float p = params[k];
            // numerically-stable softplus
            float sp = (p > 0.0f) ? (p + log1pf(expf(-p))) : log1pf(expf(p));
            acc += sp;
            ws[k] = acc;
            ws[32 + k - 1] = sp * SP_INV_DIST;   // (c[k]-c[k-1])/dist
        }
    }
}

// ---------------------------------------------------------------------------
// Per-element evaluation: uniform-knot deBoor (cubic value, quadratic deriv)
// ---------------------------------------------------------------------------
__device__ __forceinline__ float eval_one(float xin,
                                          const float* __restrict__ s_c,
                                          const float* __restrict__ s_d) {
    float x = fminf(fmaxf(xin, -15.0f), 15.0f);
    float u = fmaf(x - SP_LO, SP_INV_DIST, 3.0f);   // in [5.41, 29.59]
    int   s = (int)u;                               // trunc == floor (u > 0)
    float f = u - (float)s;

    float d0 = s_c[s - 3], d1 = s_c[s - 2], d2 = s_c[s - 1], d3 = s_c[s];
    float e0 = s_d[s - 3], e1 = s_d[s - 2], e2 = s_d[s - 1];

    float a;
    // cubic deBoor, r=1 (alpha = (f+3-j)/3), j descending
    a = f * (1.0f / 3.0f);            d3 = fmaf(a, d3 - d2, d2);
    a = (f + 1.0f) * (1.0f / 3.0f);   d2 = fmaf(a, d2 - d1, d1);
    a = (f + 2.0f) * (1.0f / 3.0f);   d1 = fmaf(a, d1 - d0, d0);
    // r=2 (alpha = (f+3-j)/2)
    a = f * 0.5f;                     d3 = fmaf(a, d3 - d2, d2);
    a = (f + 1.0f) * 0.5f;            d2 = fmaf(a, d2 - d1, d1);
    // r=3
    d3 = fmaf(f, d3 - d2, d2);        // value

    // quadratic deBoor on dcoefs (shifted knots), r=1 (alpha=(f+2-j)/2)
    a = f * 0.5f;                     e2 = fmaf(a, e2 - e1, e1);
    a = (f + 1.0f) * 0.5f;            e1 = fmaf(a, e1 - e0, e0);
    // r=2
    e2 = fmaf(f, e2 - e1, e1);        // derivative (> 0 by monotonicity)

    return fmaf(-0.5f * d3, d3, NEG_HALF_LOG_2PI) + __logf(e2);
}

// ---------------------------------------------------------------------------
// Kernel 2: grid-stride float4 elementwise map
// ---------------------------------------------------------------------------
__global__ __launch_bounds__(256) void TM_73727408603569_kernel(
        const float* __restrict__ y, const float* __restrict__ ws,
        float* __restrict__ out, int n) {
    __shared__ float s_c[32];
    __shared__ float s_d[31];
    int t = threadIdx.x;
    if (t < 32)      s_c[t] = ws[t];
    else if (t < 63) s_d[t - 32] = ws[t];
    __syncthreads();

    int n4 = n >> 2;
    int stride = gridDim.x * blockDim.x;
    const float4* y4 = reinterpret_cast<const float4*>(y);
    float4*       o4 = reinterpret_cast<float4*>(out);

    for (int i = blockIdx.x * blockDim.x + t; i < n4; i += stride) {
        float4 v = y4[i];
        float4 r;
        r.x = eval_one(v.x, s_c, s_d);
        r.y = eval_one(v.y, s_c, s_d);
        r.z = eval_one(v.z, s_c, s_d);
        r.w = eval_one(v.w, s_c, s_d);
        o4[i] = r;
    }

    // scalar tail (n not multiple of 4)
    int tail = n & 3;
    if (blockIdx.x == 0 && t < tail) {
        int idx = (n4 << 2) + t;
        out[idx] = eval_one(y[idx], s_c, s_d);
    }
}

extern "C" void kernel_launch(void* const* d_in, const int* in_sizes, int n_in,
                              void* d_out, int out_size, void* d_ws, size_t ws_size,
                              hipStream_t stream) {
    const float* params = (const float*)d_in[0];
    const float* y      = (const float*)d_in[1];
    float*       out    = (float*)d_out;
    float*       ws     = (float*)d_ws;
    int n = in_sizes[1];

    TM_precompute<<<1, 64, 0, stream>>>(params, ws);

    int n4 = n >> 2;
    int blocks = (n4 + 255) / 256;
    if (blocks > 2048) blocks = 2048;
    if (blocks < 1) blocks = 1;
    TM_73727408603569_kernel<<<blocks, 256, 0, stream>>>(y, ws, out, n);
}

// Round 2
// 34.502 us; speedup vs baseline: 1.3418x; 1.3418x over previous
//
#include <hip/hip_runtime.h>
#include <math.h>

// Spline geometry (uniform knots): lo = -18, dist = 36/29, 1/dist = 29/36
#define SP_INV_DIST (29.0f / 36.0f)
#define SP_U_OFFS   (17.5f)              // 3 - lo/dist = 3 + 18*29/36
#define NEG_HALF_LOG_2PI (-0.91893853320467274f)

// ---------------------------------------------------------------------------
// Kernel 1 (1 wave): monotonic coef transform -> per-span power-basis polys
//   ws4[0..31]  = {a0,a1,a2,a3}  value cubic in f
//   ws4[32..63] = {q0,q1,q2, 0}  derivative quadratic in f (already /dist)
// ---------------------------------------------------------------------------
__global__ void TM_precompute(const float* __restrict__ params,
                              float* __restrict__ ws) {
    __shared__ float sp[32];
    __shared__ float c[32];
    int t = threadIdx.x;
    if (t >= 1 && t < 32) {
        float p = params[t];
        sp[t] = (p > 0.0f) ? (p + log1pf(expf(-p))) : log1pf(expf(p));
    }
    __syncthreads();
    if (t == 0) {
        float acc = params[0];
        c[0] = acc;
        for (int k = 1; k < 32; ++k) { acc += sp[k]; c[k] = acc; }
    }
    __syncthreads();
    if (t < 32) {
        float4 vp = make_float4(0.f, 0.f, 0.f, 0.f);
        float4 dp = make_float4(0.f, 0.f, 0.f, 0.f);
        if (t >= 3) {
            float d0 = c[t - 3], d1 = c[t - 2], d2 = c[t - 1], d3 = c[t];
            const float SIXTH = 1.0f / 6.0f;
            float a0 = (d0 + 4.0f * d1 + d2) * SIXTH;
            float a1 = (d2 - d0) * 0.5f;
            float a2 = (d0 - 2.0f * d1 + d2) * 0.5f;
            float a3 = (d3 - d0 + 3.0f * (d1 - d2)) * SIXTH;
            vp = make_float4(a0, a1, a2, a3);
            dp = make_float4(a1 * SP_INV_DIST,
                             2.0f * a2 * SP_INV_DIST,
                             3.0f * a3 * SP_INV_DIST, 0.0f);
        }
        float4* ws4 = reinterpret_cast<float4*>(ws);
        ws4[t]      = vp;
        ws4[32 + t] = dp;
    }
}

// ---------------------------------------------------------------------------
// Per-element: clamp -> span -> 2 LDS float4 gathers -> Horner -> logprob
// ---------------------------------------------------------------------------
__device__ __forceinline__ float eval_one(float xin, const float4* __restrict__ tab) {
    float x = fminf(fmaxf(xin, -15.0f), 15.0f);
    float u = fmaf(x, SP_INV_DIST, SP_U_OFFS);      // in [5.41, 29.59]
    int   s = (int)u;
    s = min(max(s, 3), 31);                         // safety clamp
    float f = u - (float)s;
    float4 a = tab[s];
    float4 q = tab[32 + s];
    float val = fmaf(fmaf(fmaf(a.w, f, a.z), f, a.y), f, a.x);
    float der = fmaf(fmaf(q.z, f, q.y), f, q.x);    // > 0 by monotonicity
    return fmaf(-0.5f * val, val, NEG_HALF_LOG_2PI) + __logf(der);
}

// ---------------------------------------------------------------------------
// Kernel 2: one-shot, 2 independent float4s per thread (ILP=2)
// ---------------------------------------------------------------------------
__global__ __launch_bounds__(256) void TM_73727408603569_kernel(
        const float* __restrict__ y, const float* __restrict__ ws,
        float* __restrict__ out, int n4, int tail_base, int tail) {
    __shared__ float s_tab[256];
    int t = threadIdx.x;
    s_tab[t] = ws[t];
    __syncthreads();
    const float4* tab = reinterpret_cast<const float4*>(s_tab);

    const float4* y4 = reinterpret_cast<const float4*>(y);
    float4*       o4 = reinterpret_cast<float4*>(out);

    int i0 = blockIdx.x * 512 + t;
    int i1 = i0 + 256;
    bool p0 = i0 < n4, p1 = i1 < n4;
    float4 v0, v1;
    if (p0) v0 = y4[i0];
    if (p1) v1 = y4[i1];           // both loads in flight before dep chains
    if (p0) {
        float4 r;
        r.x = eval_one(v0.x, tab); r.y = eval_one(v0.y, tab);
        r.z = eval_one(v0.z, tab); r.w = eval_one(v0.w, tab);
        o4[i0] = r;
    }
    if (p1) {
        float4 r;
        r.x = eval_one(v1.x, tab); r.y = eval_one(v1.y, tab);
        r.z = eval_one(v1.z, tab); r.w = eval_one(v1.w, tab);
        o4[i1] = r;
    }

    // scalar tail (n not multiple of 4)
    if (blockIdx.x == 0 && t < tail) {
        int idx = tail_base + t;
        out[idx] = eval_one(y[idx], tab);
    }
}

extern "C" void kernel_launch(void* const* d_in, const int* in_sizes, int n_in,
                              void* d_out, int out_size, void* d_ws, size_t ws_size,
                              hipStream_t stream) {
    const float* params = (const float*)d_in[0];
    const float* y      = (const float*)d_in[1];
    float*       out    = (float*)d_out;
    float*       ws     = (float*)d_ws;
    int n  = in_sizes[1];
    int n4 = n >> 2;
    int tail = n & 3;

    TM_precompute<<<1, 64, 0, stream>>>(params, ws);

    int blocks = (n4 + 511) / 512;
    if (blocks < 1) blocks = 1;
    TM_73727408603569_kernel<<<blocks, 256, 0, stream>>>(y, ws, out, n4,
                                                         n4 << 2, tail);
}